// Round 1
// baseline (846.789 us; speedup 1.0000x reference)
//
#include <hip/hip_runtime.h>

// Problem constants (from reference)
#define NVOX 150000
#define NPAD 150016          // 2344 * 64 row tiles
#define CCH  256
#define ZROW NVOX            // zero row for -1 neighbors (pad rows zeroed)

typedef __attribute__((ext_vector_type(8))) short bfrag_t;   // 8 bf16 = 4 VGPRs
typedef __attribute__((ext_vector_type(4))) float accfrag_t; // 4 fp32

__device__ __forceinline__ void async_copy16(const void* g, void* l) {
  __builtin_amdgcn_global_load_lds(
      (const __attribute__((address_space(1))) void*)g,
      (__attribute__((address_space(3))) void*)l, 16, 0, 0);
}

__device__ __forceinline__ unsigned short f2bf(float x) {
  unsigned int u = __float_as_uint(x);
  unsigned int r = (u + 0x7FFFu + ((u >> 16) & 1u)) >> 16;  // RNE
  return (unsigned short)r;
}

// ---- feats fp32 -> bf16 (padded, pad rows zeroed) ----
__global__ __launch_bounds__(256) void cvt_feats_kernel(
    const float* __restrict__ f, unsigned short* __restrict__ o) {
  int t = blockIdx.x * 256 + threadIdx.x;        // 8 elements per thread
  int row = t >> 5;                              // 32 threads per 256-ch row
  bfrag_t pack;
  if (row < NVOX) {
    const float4* fp = (const float4*)f;
    float4 a = fp[2 * t];
    float4 b = fp[2 * t + 1];
    float v[8] = {a.x, a.y, a.z, a.w, b.x, b.y, b.z, b.w};
#pragma unroll
    for (int i = 0; i < 8; ++i) pack[i] = (short)f2bf(v[i]);
  } else {
#pragma unroll
    for (int i = 0; i < 8; ++i) pack[i] = 0;
  }
  *(bfrag_t*)(o + (size_t)t * 8) = pack;
}

// ---- weights fp32 [3][cin][cout] -> bf16 transposed Wt[9][cout][cin] ----
__global__ __launch_bounds__(256) void cvt_w_kernel(
    const float* __restrict__ w1, const float* __restrict__ w2,
    const float* __restrict__ w3, unsigned short* __restrict__ o) {
  int t = blockIdx.x * 256 + threadIdx.x;  // 9*65536 total
  int g9 = t >> 16;                        // conv*3+tap, 0..8
  int idx = t & 65535;
  int n = idx >> 8, k = idx & 255;
  const float* w = (g9 < 3) ? w1 : ((g9 < 6) ? w2 : w3);
  int tap = (g9 < 3) ? g9 : ((g9 < 6) ? g9 - 3 : g9 - 6);
  o[t] = f2bf(w[(tap * 256 + k) * 256 + n]);
}

// ---- fused: 3x (3-tap gathered GEMM) + BN+sigmoid sum + gate by feats ----
__global__ __launch_bounds__(256) void recon_kernel(
    const unsigned short* __restrict__ F16, const float* __restrict__ F32,
    const unsigned short* __restrict__ Wt,
    const int* __restrict__ nbrx, const int* __restrict__ nbry,
    const int* __restrict__ nbrz,
    const float* __restrict__ g1, const float* __restrict__ b1,
    const float* __restrict__ g2, const float* __restrict__ b2,
    const float* __restrict__ g3, const float* __restrict__ b3,
    float* __restrict__ out) {
  // LDS A tile: 64 rows x 256 k bf16, 16B chunks XOR-swizzled: phys = log ^ (row&31)
  __shared__ unsigned short Asmem[64 * 256];  // 32 KB
  const int tid = threadIdx.x;
  const int w = tid >> 6, lane = tid & 63;
  const int m = lane & 15, quad = lane >> 4;
  const int m0 = blockIdx.x * 64;
  const int wn0 = blockIdx.y * 128 + w * 32;
  const float RSQ = 0.9999950000374998f;  // rsqrt(1+1e-5)

  accfrag_t sum[4][2];
#pragma unroll
  for (int mt = 0; mt < 4; ++mt)
#pragma unroll
    for (int nt = 0; nt < 2; ++nt) sum[mt][nt] = (accfrag_t){0.f, 0.f, 0.f, 0.f};

  for (int conv = 0; conv < 3; ++conv) {
    const int* nbr = (conv == 0) ? nbrx : ((conv == 1) ? nbry : nbrz);
    accfrag_t acc[4][2];
#pragma unroll
    for (int mt = 0; mt < 4; ++mt)
#pragma unroll
      for (int nt = 0; nt < 2; ++nt) acc[mt][nt] = (accfrag_t){0.f, 0.f, 0.f, 0.f};

    for (int tap = 0; tap < 3; ++tap) {
      const unsigned short* Wtap = Wt + (((size_t)(conv * 3 + tap)) << 16);
      __syncthreads();  // protect LDS from previous tap's readers
      // gather-stage 64 rows x 512B; each wave: 16 rows via 8 issues of 2 rows
#pragma unroll
      for (int iss = 0; iss < 8; ++iss) {
        int lr = (w << 4) + (iss << 1) + (lane >> 5);
        int gr = m0 + lr;
        int nbi = (gr < NVOX) ? nbr[gr * 3 + tap] : -1;
        int srow = (nbi >= 0) ? nbi : ZROW;
        int clog = (lane & 31) ^ (lr & 31);  // source-side XOR swizzle
        const unsigned short* src = F16 + ((size_t)srow << 8) + (clog << 3);
        char* dst = (char*)Asmem + ((size_t)((w << 4) + (iss << 1)) << 9);
        async_copy16(src, dst);
      }
      __syncthreads();
      // K loop: 8 steps of 32
#pragma unroll
      for (int ks = 0; ks < 8; ++ks) {
        const int k0 = ks * 32;
        bfrag_t a[4], bb[2];
#pragma unroll
        for (int mt = 0; mt < 4; ++mt) {
          int row = mt * 16 + m;
          int cph = ((k0 >> 3) + quad) ^ (row & 31);
          a[mt] = *(const bfrag_t*)((const char*)Asmem + row * 512 + cph * 16);
        }
#pragma unroll
        for (int nt = 0; nt < 2; ++nt) {
          int col = wn0 + nt * 16 + m;
          bb[nt] = *(const bfrag_t*)(Wtap + col * 256 + k0 + quad * 8);
        }
#pragma unroll
        for (int mt = 0; mt < 4; ++mt)
#pragma unroll
          for (int nt = 0; nt < 2; ++nt)
            acc[mt][nt] = __builtin_amdgcn_mfma_f32_16x16x32_bf16(
                a[mt], bb[nt], acc[mt][nt], 0, 0, 0);
      }
    }
    // per-conv epilogue: BN (eval) + sigmoid, accumulate
    const float* gp = (conv == 0) ? g1 : ((conv == 1) ? g2 : g3);
    const float* bp = (conv == 0) ? b1 : ((conv == 1) ? b2 : b3);
#pragma unroll
    for (int nt = 0; nt < 2; ++nt) {
      int c = wn0 + nt * 16 + m;
      float sc = gp[c] * RSQ;
      float bi = bp[c];
#pragma unroll
      for (int mt = 0; mt < 4; ++mt)
#pragma unroll
        for (int r = 0; r < 4; ++r) {
          float y = acc[mt][nt][r];
          float sg = 1.0f / (1.0f + __expf(-(y * sc + bi)));
          sum[mt][nt][r] += sg;
        }
    }
  }
  // final gate: out = sum * feats (fp32)
#pragma unroll
  for (int mt = 0; mt < 4; ++mt)
#pragma unroll
    for (int r = 0; r < 4; ++r) {
      int row = m0 + mt * 16 + quad * 4 + r;
      if (row < NVOX) {
#pragma unroll
        for (int nt = 0; nt < 2; ++nt) {
          int c = wn0 + nt * 16 + m;
          size_t off = ((size_t)row << 8) + c;
          out[off] = sum[mt][nt][r] * F32[off];
        }
      }
    }
}

extern "C" void kernel_launch(void* const* d_in, const int* in_sizes, int n_in,
                              void* d_out, int out_size, void* d_ws, size_t ws_size,
                              hipStream_t stream) {
  const float* feats = (const float*)d_in[0];
  const float* w1 = (const float*)d_in[1];
  const float* w2 = (const float*)d_in[2];
  const float* w3 = (const float*)d_in[3];
  const float* g1 = (const float*)d_in[4];
  const float* b1 = (const float*)d_in[5];
  const float* g2 = (const float*)d_in[6];
  const float* b2 = (const float*)d_in[7];
  const float* g3 = (const float*)d_in[8];
  const float* b3 = (const float*)d_in[9];
  const int* nbrx = (const int*)d_in[10];
  const int* nbry = (const int*)d_in[11];
  const int* nbrz = (const int*)d_in[12];
  float* out = (float*)d_out;

  // ws layout: F16 (NPAD*256 bf16 = 76.8 MB) | Wt (9*65536 bf16 = 1.18 MB)
  unsigned short* F16 = (unsigned short*)d_ws;
  unsigned short* Wt = F16 + (size_t)NPAD * CCH;

  cvt_feats_kernel<<<NPAD * CCH / 8 / 256, 256, 0, stream>>>(feats, F16);
  cvt_w_kernel<<<9 * 65536 / 256, 256, 0, stream>>>(w1, w2, w3, Wt);
  dim3 grid(NPAD / 64, 2);
  recon_kernel<<<grid, 256, 0, stream>>>(F16, feats, Wt, nbrx, nbry, nbrz,
                                         g1, b1, g2, b2, g3, b3, out);
}